// Round 2
// baseline (273.149 us; speedup 1.0000x reference)
//
#include <hip/hip_runtime.h>

#define NPOS 65536   // 256*256

typedef __attribute__((ext_vector_type(8))) short bf16x8;
typedef __attribute__((ext_vector_type(4))) float f32x4;

#if __has_builtin(__builtin_amdgcn_exp2f)
#define EXP2F(x) __builtin_amdgcn_exp2f(x)
#else
#define EXP2F(x) __expf((x) * 0.6931471805599453f)
#endif
#if __has_builtin(__builtin_amdgcn_rcpf)
#define RCPF(x) __builtin_amdgcn_rcpf(x)
#else
#define RCPF(x) (1.0f / (x))
#endif

static __device__ __forceinline__ unsigned short f2bf(float f) {
  union { float f; unsigned int u; } v; v.f = f;
  unsigned int r = v.u + 0x7fffu + ((v.u >> 16) & 1u);
  return (unsigned short)(r >> 16);
}
static __device__ __forceinline__ float bf2f(unsigned short u) {
  union { unsigned int u; float f; } v; v.u = ((unsigned int)u) << 16;
  return v.f;
}
static __device__ __forceinline__ float lo_bf(unsigned int u) {
  union { unsigned int u; float f; } v; v.u = u << 16; return v.f;
}
static __device__ __forceinline__ float hi_bf(unsigned int u) {
  union { unsigned int u; float f; } v; v.u = u & 0xffff0000u; return v.f;
}
// (hi.bf16_trunc << 16) | lo.bf16_trunc  — 1 instruction (v_perm_b32)
static __device__ __forceinline__ unsigned int permpack(float hi, float lo) {
  union { float f; unsigned int u; } a, b;
  a.f = hi; b.f = lo;
#if __has_builtin(__builtin_amdgcn_perm)
  return __builtin_amdgcn_perm(a.u, b.u, 0x07060302u);
#else
  return (a.u & 0xffff0000u) | (b.u >> 16);
#endif
}

// ---------------- K0: pack transposed bf16 weights ----------------
// Wq gets 1/sqrt(32) * log2(e) folded (softmax uses exp2, no max-sub).
__global__ void k_pack(const float* __restrict__ Wq, const float* __restrict__ Wk,
                       const float* __restrict__ Wv, const float* __restrict__ Wg,
                       const float* __restrict__ Wo,
                       ushort* __restrict__ WT, ushort* __restrict__ WoT) {
  int idx = blockIdx.x * blockDim.x + threadIdx.x;
  if (idx < 512 * 128) {
    int n = idx >> 7, k = idx & 127;
    int nn = n & 127;
    float val;
    if (n < 128)      val = Wq[k * 128 + nn] * (0.17677669529663687f * 1.4426950408889634f);
    else if (n < 256) val = Wk[k * 128 + nn];
    else if (n < 384) val = Wv[k * 128 + nn];
    else              val = Wg[k * 128 + nn];
    WT[idx] = f2bf(val);
  } else if (idx < 512 * 128 + 128 * 128) {
    int j = idx - 512 * 128;
    int n = j >> 7, k = j & 127;
    WoT[j] = f2bf(Wo[k * 128 + n]);
  }
}

// ---------------- K1: fused LN + bias + QKVG proj ----------------
// Restructured R1: block = 16 rows, 2 waves split SECTIONS (wave0: q,k + bias;
// wave1: v,gate). LN computed per-wave (same rows -> L1 hit). Grid 4096.
// Waves double vs R0 (8192 total), per-wave serial path halves (64 MFMAs).
// LDS 10496B -> 15 blocks/CU resident. No barriers (wave-private staging).
__global__ __launch_bounds__(128, 4) void k_lnproj(
    const float* __restrict__ in, const float* __restrict__ gamma,
    const float* __restrict__ beta, const float* __restrict__ Wb,
    const ushort* __restrict__ WT, const float* __restrict__ bg,
    ushort* __restrict__ q, ushort* __restrict__ kmat, ushort* __restrict__ vT,
    ushort* __restrict__ gate, ushort* __restrict__ biasB) {
  __shared__ __align__(16) ushort stg[5248];   // wave0: [0,2176), wave1: [2176,5248)
  int t = threadIdx.x, wv = t >> 6, lane = t & 63;
  int n = lane & 15, g = lane >> 4;
  int row0 = blockIdx.x * 16;
  int i = row0 >> 8, j0b = row0 & 255;
  int myrow = row0 + n;
  const float* rp = in + (size_t)myrow * 128;

  // ---- LN in registers (both waves, same 16 rows) ----
  float xv[32];
  float s = 0.f, ss = 0.f;
  #pragma unroll
  for (int kc = 0; kc < 4; kc++)
    #pragma unroll
    for (int pr = 0; pr < 2; pr++) {
      float4 v = *(const float4*)(rp + kc * 32 + g * 8 + pr * 4);
      int o = kc * 8 + pr * 4;
      xv[o] = v.x; xv[o+1] = v.y; xv[o+2] = v.z; xv[o+3] = v.w;
      s  += v.x + v.y + v.z + v.w;
      ss += v.x*v.x + v.y*v.y + v.z*v.z + v.w*v.w;
    }
  s  += __shfl_xor(s, 16, 64);  s  += __shfl_xor(s, 32, 64);
  ss += __shfl_xor(ss, 16, 64); ss += __shfl_xor(ss, 32, 64);
  float mu  = s * (1.0f / 128.0f);
  float var = ss * (1.0f / 128.0f) - mu * mu;
  float rs  = rsqrtf(var + 1e-5f);
  float p0 = 0.f, p1 = 0.f, p2 = 0.f, p3 = 0.f;
  #pragma unroll
  for (int kc = 0; kc < 4; kc++)
    #pragma unroll
    for (int pr = 0; pr < 2; pr++) {
      int c0 = kc * 32 + g * 8 + pr * 4;
      float4 g4 = *(const float4*)(gamma + c0);
      float4 b4 = *(const float4*)(beta + c0);
      int o = kc * 8 + pr * 4;
      #pragma unroll
      for (int r = 0; r < 4; r++) {
        float xn = (xv[o + r] - mu) * rs * (&g4.x)[r] + (&b4.x)[r];
        xv[o + r] = xn;
        if (wv == 0) {   // bias projection only needed once
          float4 w = ((const float4*)Wb)[c0 + r];
          p0 += xn * w.x; p1 += xn * w.y; p2 += xn * w.z; p3 += xn * w.w;
        }
      }
    }
  if (wv == 0) {
    p0 += __shfl_xor(p0, 16, 64); p0 += __shfl_xor(p0, 32, 64);
    p1 += __shfl_xor(p1, 16, 64); p1 += __shfl_xor(p1, 32, 64);
    p2 += __shfl_xor(p2, 16, 64); p2 += __shfl_xor(p2, 32, 64);
    p3 += __shfl_xor(p3, 16, 64); p3 += __shfl_xor(p3, 32, 64);
    if (g == 0) {
      const float l2e = 1.4426950408889634f;
      biasB[0 * NPOS + myrow] = f2bf(p0 * l2e);
      biasB[1 * NPOS + myrow] = f2bf(p1 * l2e);
      biasB[2 * NPOS + myrow] = f2bf(p2 * l2e);
      biasB[3 * NPOS + myrow] = f2bf(p3 * l2e);
    }
  }
  bf16x8 a[4];
  #pragma unroll
  for (int kc = 0; kc < 4; kc++)
    #pragma unroll
    for (int e = 0; e < 8; e++) a[kc][e] = (short)f2bf(xv[kc * 8 + e]);

  if (wv == 0) {
    // ---- sections 0 (q), 1 (k) ----
    ushort* st = stg;
    #pragma unroll
    for (int s4 = 0; s4 < 2; s4++) {
      f32x4 acc[8];
      #pragma unroll
      for (int ntl = 0; ntl < 8; ntl++) {
        f32x4 c = {0.f, 0.f, 0.f, 0.f};
        #pragma unroll
        for (int kc = 0; kc < 4; kc++) {
          bf16x8 b = *(const bf16x8*)(WT + (size_t)(s4 * 128 + ntl * 16 + n) * 128 + kc * 32 + g * 8);
          c = __builtin_amdgcn_mfma_f32_16x16x32_bf16(a[kc], b, c, 0, 0, 0);
        }
        acc[ntl] = c;
      }
      #pragma unroll
      for (int ntl = 0; ntl < 8; ntl++)
        #pragma unroll
        for (int r = 0; r < 4; r++)
          st[(g * 4 + r) * 136 + ntl * 16 + n] = f2bf(acc[ntl][r]);
      ushort* dst = (s4 == 0) ? q : kmat;
      int row = lane >> 2, off = (lane & 3) * 8;
      #pragma unroll
      for (int h = 0; h < 4; h++)
        *(bf16x8*)(dst + ((size_t)(i * 4 + h) * 256 + j0b + row) * 32 + off) =
            *(const bf16x8*)(&st[row * 136 + h * 32 + off]);
    }
  } else {
    ushort* st = stg + 2176;
    // ---- section 2 (v), transposed staging ----
    {
      f32x4 acc[8];
      #pragma unroll
      for (int ntl = 0; ntl < 8; ntl++) {
        f32x4 c = {0.f, 0.f, 0.f, 0.f};
        #pragma unroll
        for (int kc = 0; kc < 4; kc++) {
          bf16x8 b = *(const bf16x8*)(WT + (size_t)(256 + ntl * 16 + n) * 128 + kc * 32 + g * 8);
          c = __builtin_amdgcn_mfma_f32_16x16x32_bf16(a[kc], b, c, 0, 0, 0);
        }
        acc[ntl] = c;
      }
      #pragma unroll
      for (int ntl = 0; ntl < 8; ntl++) {
        uint2 vp;
        vp.x = (unsigned int)f2bf(acc[ntl][0]) | ((unsigned int)f2bf(acc[ntl][1]) << 16);
        vp.y = (unsigned int)f2bf(acc[ntl][2]) | ((unsigned int)f2bf(acc[ntl][3]) << 16);
        *(uint2*)(&st[(ntl * 16 + n) * 24 + g * 4]) = vp;
      }
      #pragma unroll
      for (int it = 0; it < 4; it++) {
        int c = it * 64 + lane;
        int hd = c >> 1, half = c & 1;
        bf16x8 vv = *(const bf16x8*)(&st[hd * 24 + half * 8]);
        int h = hd >> 5, d = hd & 31;
        *(bf16x8*)(vT + ((size_t)(i * 4 + h) * 32 + d) * 256 + j0b + half * 8) = vv;
      }
    }
    // ---- section 3 (gate) ----
    {
      f32x4 acc[8];
      #pragma unroll
      for (int ntl = 0; ntl < 8; ntl++) {
        f32x4 c = {0.f, 0.f, 0.f, 0.f};
        #pragma unroll
        for (int kc = 0; kc < 4; kc++) {
          bf16x8 b = *(const bf16x8*)(WT + (size_t)(384 + ntl * 16 + n) * 128 + kc * 32 + g * 8);
          c = __builtin_amdgcn_mfma_f32_16x16x32_bf16(a[kc], b, c, 0, 0, 0);
        }
        acc[ntl] = c;
      }
      #pragma unroll
      for (int ntl = 0; ntl < 8; ntl++)
        #pragma unroll
        for (int r = 0; r < 4; r++) {
          float val = 1.0f / (1.0f + __expf(-(acc[ntl][r] + bg[ntl * 16 + n])));
          st[(g * 4 + r) * 136 + ntl * 16 + n] = f2bf(val);
        }
      #pragma unroll
      for (int it = 0; it < 4; it++) {
        int c = it * 64 + lane;
        int row = c >> 4, off = (c & 15) * 8;
        *(bf16x8*)(gate + (size_t)(row0 + row) * 128 + off) =
            *(const bf16x8*)(&st[row * 136 + off]);
      }
    }
  }
}

// ---------------- K2: attention, S^T orientation; no barriers, no max-sub ---
#define PST 40   // P-stage row stride (ushorts; 80B, 16B-aligned)
__global__ __launch_bounds__(256, 4) void k_attn(
    const ushort* __restrict__ q, const ushort* __restrict__ kmat,
    const ushort* __restrict__ vT, const ushort* __restrict__ gate,
    const ushort* __restrict__ biasB, ushort* __restrict__ gctx) {
  __shared__ __align__(16) float stg[4][16 * 36];   // 2.3KB/wave (P + ctx stage)
  int i = blockIdx.x >> 3, h = (blockIdx.x >> 1) & 3, jh = blockIdx.x & 1;
  int t = threadIdx.x, wv = t >> 6, lane = t & 63;
  int n = lane & 15, g = lane >> 4;
  const ushort* qb = q    + (size_t)(i * 4 + h) * 8192;
  const ushort* kb = kmat + (size_t)(i * 4 + h) * 8192;
  const ushort* vb = vT   + (size_t)(i * 4 + h) * 8192;
  const ushort* bb = biasB + (size_t)h * NPOS;
  ushort* Pw = (ushort*)stg[wv];
  float* CT = stg[wv];

  for (int jj = 0; jj < 2; jj++) {
    int j0 = jh * 128 + wv * 32 + jj * 16;
    // Q as B-operand (col = query), K as A-operand (row = key) -> S^T tiles
    bf16x8 bq = *(const bf16x8*)(qb + (size_t)(j0 + n) * 32 + g * 8);
    f32x4 s[16];
    #pragma unroll
    for (int kt = 0; kt < 16; kt++) {
      uint2 bv = *(const uint2*)(bb + (size_t)(j0 + n) * 256 + kt * 16 + g * 4);
      bf16x8 ak = *(const bf16x8*)(kb + (size_t)(kt * 16 + n) * 32 + g * 8);
      f32x4 c;
      c[0] = lo_bf(bv.x); c[1] = hi_bf(bv.x);
      c[2] = lo_bf(bv.y); c[3] = hi_bf(bv.y);
      s[kt] = __builtin_amdgcn_mfma_f32_16x16x32_bf16(ak, bq, c, 0, 0, 0);
    }
    // softmax: exp2 (log2e pre-folded), no max-sub (scores bounded ~|2|)
    f32x4 a4 = {0.f, 0.f, 0.f, 0.f};
    #pragma unroll
    for (int kt = 0; kt < 16; kt++) {
      #pragma unroll
      for (int r = 0; r < 4; r++) s[kt][r] = EXP2F(s[kt][r]);
      a4 += s[kt];
    }
    float sm = (a4[0] + a4[1]) + (a4[2] + a4[3]);
    sm += __shfl_xor(sm, 16, 64);
    sm += __shfl_xor(sm, 32, 64);
    float inv = RCPF(sm);   // per-lane: this lane's query = n
    // PV interleaved with P staging in 32-key chunks (wave-private LDS,
    // in-order DS pipe => no waits/barriers needed)
    f32x4 ctx0 = {0.f, 0.f, 0.f, 0.f}, ctx1 = {0.f, 0.f, 0.f, 0.f};
    #pragma unroll
    for (int c8 = 0; c8 < 8; c8++) {
      #pragma unroll
      for (int t2 = 0; t2 < 2; t2++) {
        int kt = c8 * 2 + t2;
        uint2 pp;
        pp.x = permpack(s[kt][1] * inv, s[kt][0] * inv);
        pp.y = permpack(s[kt][3] * inv, s[kt][2] * inv);
        *(uint2*)(&Pw[n * PST + t2 * 16 + g * 4]) = pp;   // row=query n, 4 keys
      }
      bf16x8 ap = *(const bf16x8*)(&Pw[n * PST + g * 8]);
      bf16x8 v0 = *(const bf16x8*)(vb + (size_t)n * 256 + c8 * 32 + g * 8);
      bf16x8 v1 = *(const bf16x8*)(vb + (size_t)(16 + n) * 256 + c8 * 32 + g * 8);
      ctx0 = __builtin_amdgcn_mfma_f32_16x16x32_bf16(ap, v0, ctx0, 0, 0, 0);
      ctx1 = __builtin_amdgcn_mfma_f32_16x16x32_bf16(ap, v1, ctx1, 0, 0, 0);
    }
    // ctx stage f32 (stride 36), gate applied on coalesced drain
    #pragma unroll
    for (int r = 0; r < 4; r++) {
      CT[(g * 4 + r) * 36 + n] = ctx0[r];
      CT[(g * 4 + r) * 36 + 16 + n] = ctx1[r];
    }
    {
      int row = lane >> 2, part = lane & 3;
      size_t o = ((size_t)i * 256 + j0 + row) * 128 + h * 32 + part * 8;
      bf16x8 gt = *(const bf16x8*)(gate + o);
      bf16x8 outp;
      #pragma unroll
      for (int e = 0; e < 8; e++)
        outp[e] = (short)f2bf(CT[row * 36 + part * 8 + e] * bf2f((unsigned short)gt[e]));
      *(bf16x8*)(gctx + o) = outp;
    }
  }
}

// ---------------- K3: out-proj + bias + residual ----------------
// Restructured R1: block = 16 rows, 2 waves split output columns (ntl 0-3/4-7),
// one barrier before the shared coalesced drain. Grid 4096.
__global__ __launch_bounds__(128, 4) void k_out(
    const ushort* __restrict__ gctx, const ushort* __restrict__ WoT,
    const float* __restrict__ bo, const float* __restrict__ in0,
    float* __restrict__ out) {
  __shared__ __align__(16) float CT[16 * 132];   // 8448B
  int t = threadIdx.x, wv = t >> 6, lane = t & 63;
  int n = lane & 15, g = lane >> 4;
  int row0 = blockIdx.x * 16;
  bf16x8 a[4];
  #pragma unroll
  for (int kc = 0; kc < 4; kc++)
    a[kc] = *(const bf16x8*)(gctx + (size_t)(row0 + n) * 128 + kc * 32 + g * 8);
  #pragma unroll
  for (int ntl2 = 0; ntl2 < 4; ntl2++) {
    int ntl = wv * 4 + ntl2;
    f32x4 acc = {0.f, 0.f, 0.f, 0.f};
    #pragma unroll
    for (int kc = 0; kc < 4; kc++) {
      bf16x8 b = *(const bf16x8*)(WoT + (size_t)(ntl * 16 + n) * 128 + kc * 32 + g * 8);
      acc = __builtin_amdgcn_mfma_f32_16x16x32_bf16(a[kc], b, acc, 0, 0, 0);
    }
    float bov = bo[ntl * 16 + n];
    #pragma unroll
    for (int r = 0; r < 4; r++)
      CT[(g * 4 + r) * 132 + ntl * 16 + n] = acc[r] + bov;
  }
  __syncthreads();
  #pragma unroll
  for (int it = 0; it < 4; it++) {
    int c = it * 128 + t;
    int row = c >> 5, off = (c & 31) * 4;
    f32x4 v = *(const f32x4*)(&CT[row * 132 + off]);
    size_t o = (size_t)(row0 + row) * 128 + off;
    f32x4 r4 = *(const f32x4*)(in0 + o);
    v[0] += r4[0]; v[1] += r4[1]; v[2] += r4[2]; v[3] += r4[3];
    *(f32x4*)(out + o) = v;
  }
}

extern "C" void kernel_launch(void* const* d_in, const int* in_sizes, int n_in,
                              void* d_out, int out_size, void* d_ws, size_t ws_size,
                              hipStream_t stream) {
  const float* in0   = (const float*)d_in[0];
  const float* gamma = (const float*)d_in[1];
  const float* beta  = (const float*)d_in[2];
  const float* Wq    = (const float*)d_in[3];
  const float* Wk    = (const float*)d_in[4];
  const float* Wv    = (const float*)d_in[5];
  const float* Wb    = (const float*)d_in[6];
  const float* Wg    = (const float*)d_in[7];
  const float* bg    = (const float*)d_in[8];
  const float* Wo    = (const float*)d_in[9];
  const float* bo    = (const float*)d_in[10];
  float* out = (float*)d_out;
  char* ws = (char*)d_ws;

  const size_t MB = 1024 * 1024;
  ushort* qbuf  = (ushort*)(ws);              // 16 MB: [ih][j][d]
  ushort* kbuf  = (ushort*)(ws + 16 * MB);    // 16 MB: [ih][k][d]
  ushort* vTbuf = (ushort*)(ws + 32 * MB);    // 16 MB: [ih][d][k]
  ushort* gbuf  = (ushort*)(ws + 48 * MB);    // 16 MB: gate [pos][128]
  ushort* gctx  = (ushort*)(ws + 64 * MB);    // 16 MB: [pos][128]
  ushort* biasB = (ushort*)(ws + 80 * MB);    // 512 KB: [h][j*256+k] * log2e
  ushort* WT    = (ushort*)(ws + 81 * MB);    // 128 KB
  ushort* WoT   = (ushort*)(ws + 81 * MB + 128 * 1024);  // 32 KB

  k_pack  <<<320, 256, 0, stream>>>(Wq, Wk, Wv, Wg, Wo, WT, WoT);
  k_lnproj<<<4096, 128, 0, stream>>>(in0, gamma, beta, Wb, WT, bg,
                                     qbuf, kbuf, vTbuf, gbuf, biasB);
  k_attn  <<<2048, 256, 0, stream>>>(qbuf, kbuf, vTbuf, gbuf, biasB, gctx);
  k_out   <<<4096, 128, 0, stream>>>(gctx, WoT, bo, in0, out);
}

// Round 3
// 242.871 us; speedup vs baseline: 1.1247x; 1.1247x over previous
//
#include <hip/hip_runtime.h>

#define NPOS 65536   // 256*256

typedef __attribute__((ext_vector_type(8))) short bf16x8;
typedef __attribute__((ext_vector_type(4))) float f32x4;

#if __has_builtin(__builtin_amdgcn_exp2f)
#define EXP2F(x) __builtin_amdgcn_exp2f(x)
#else
#define EXP2F(x) __expf((x) * 0.6931471805599453f)
#endif
#if __has_builtin(__builtin_amdgcn_rcpf)
#define RCPF(x) __builtin_amdgcn_rcpf(x)
#else
#define RCPF(x) (1.0f / (x))
#endif

static __device__ __forceinline__ unsigned short f2bf(float f) {
  union { float f; unsigned int u; } v; v.f = f;
  unsigned int r = v.u + 0x7fffu + ((v.u >> 16) & 1u);
  return (unsigned short)(r >> 16);
}
static __device__ __forceinline__ float bf2f(unsigned short u) {
  union { unsigned int u; float f; } v; v.u = ((unsigned int)u) << 16;
  return v.f;
}
static __device__ __forceinline__ float lo_bf(unsigned int u) {
  union { unsigned int u; float f; } v; v.u = u << 16; return v.f;
}
static __device__ __forceinline__ float hi_bf(unsigned int u) {
  union { unsigned int u; float f; } v; v.u = u & 0xffff0000u; return v.f;
}
// (hi.bf16_trunc << 16) | lo.bf16_trunc  — 1 instruction (v_perm_b32)
static __device__ __forceinline__ unsigned int permpack(float hi, float lo) {
  union { float f; unsigned int u; } a, b;
  a.f = hi; b.f = lo;
#if __has_builtin(__builtin_amdgcn_perm)
  return __builtin_amdgcn_perm(a.u, b.u, 0x07060302u);
#else
  return (a.u & 0xffff0000u) | (b.u >> 16);
#endif
}

// ---------------- K0: pack transposed bf16 weights ----------------
// Wq gets 1/sqrt(32) * log2(e) folded (softmax uses exp2, no max-sub).
__global__ void k_pack(const float* __restrict__ Wq, const float* __restrict__ Wk,
                       const float* __restrict__ Wv, const float* __restrict__ Wg,
                       const float* __restrict__ Wo,
                       ushort* __restrict__ WT, ushort* __restrict__ WoT) {
  int idx = blockIdx.x * blockDim.x + threadIdx.x;
  if (idx < 512 * 128) {
    int n = idx >> 7, k = idx & 127;
    int nn = n & 127;
    float val;
    if (n < 128)      val = Wq[k * 128 + nn] * (0.17677669529663687f * 1.4426950408889634f);
    else if (n < 256) val = Wk[k * 128 + nn];
    else if (n < 384) val = Wv[k * 128 + nn];
    else              val = Wg[k * 128 + nn];
    WT[idx] = f2bf(val);
  } else if (idx < 512 * 128 + 128 * 128) {
    int j = idx - 512 * 128;
    int n = j >> 7, k = j & 127;
    WoT[j] = f2bf(Wo[k * 128 + n]);
  }
}

// ---------------- K1: fused LN + bias + QKVG proj; 128 thr, no barriers -----
// block = 32 rows (grid 2048); wave = 16 rows. bias stored natural [h][pos]*log2e.
// (R0 structure — measured 85.6 us; R1 section-split regressed to 96.8, reverted)
__global__ __launch_bounds__(128, 4) void k_lnproj(
    const float* __restrict__ in, const float* __restrict__ gamma,
    const float* __restrict__ beta, const float* __restrict__ Wb,
    const ushort* __restrict__ WT, const float* __restrict__ bg,
    ushort* __restrict__ q, ushort* __restrict__ kmat, ushort* __restrict__ vT,
    ushort* __restrict__ gate, ushort* __restrict__ biasB) {
  __shared__ __align__(16) ushort stg[2][3072];   // 6 KB per-wave staging
  int t = threadIdx.x, wv = t >> 6, lane = t & 63;
  int n = lane & 15, g = lane >> 4;
  int row0 = blockIdx.x * 32;
  int i = row0 >> 8, j0b = row0 & 255;
  int m0 = wv * 16;
  int myrow = row0 + m0 + n;
  const float* rp = in + (size_t)myrow * 128;

  // ---- LN in registers ----
  float xv[32];
  float s = 0.f, ss = 0.f;
  #pragma unroll
  for (int kc = 0; kc < 4; kc++)
    #pragma unroll
    for (int pr = 0; pr < 2; pr++) {
      float4 v = *(const float4*)(rp + kc * 32 + g * 8 + pr * 4);
      int o = kc * 8 + pr * 4;
      xv[o] = v.x; xv[o+1] = v.y; xv[o+2] = v.z; xv[o+3] = v.w;
      s  += v.x + v.y + v.z + v.w;
      ss += v.x*v.x + v.y*v.y + v.z*v.z + v.w*v.w;
    }
  s  += __shfl_xor(s, 16, 64);  s  += __shfl_xor(s, 32, 64);
  ss += __shfl_xor(ss, 16, 64); ss += __shfl_xor(ss, 32, 64);
  float mu  = s * (1.0f / 128.0f);
  float var = ss * (1.0f / 128.0f) - mu * mu;
  float rs  = rsqrtf(var + 1e-5f);
  float p0 = 0.f, p1 = 0.f, p2 = 0.f, p3 = 0.f;
  #pragma unroll
  for (int kc = 0; kc < 4; kc++)
    #pragma unroll
    for (int pr = 0; pr < 2; pr++) {
      int c0 = kc * 32 + g * 8 + pr * 4;
      float4 g4 = *(const float4*)(gamma + c0);
      float4 b4 = *(const float4*)(beta + c0);
      int o = kc * 8 + pr * 4;
      #pragma unroll
      for (int r = 0; r < 4; r++) {
        float xn = (xv[o + r] - mu) * rs * (&g4.x)[r] + (&b4.x)[r];
        xv[o + r] = xn;
        float4 w = ((const float4*)Wb)[c0 + r];
        p0 += xn * w.x; p1 += xn * w.y; p2 += xn * w.z; p3 += xn * w.w;
      }
    }
  p0 += __shfl_xor(p0, 16, 64); p0 += __shfl_xor(p0, 32, 64);
  p1 += __shfl_xor(p1, 16, 64); p1 += __shfl_xor(p1, 32, 64);
  p2 += __shfl_xor(p2, 16, 64); p2 += __shfl_xor(p2, 32, 64);
  p3 += __shfl_xor(p3, 16, 64); p3 += __shfl_xor(p3, 32, 64);
  if (g == 0) {
    const float l2e = 1.4426950408889634f;
    biasB[0 * NPOS + myrow] = f2bf(p0 * l2e);
    biasB[1 * NPOS + myrow] = f2bf(p1 * l2e);
    biasB[2 * NPOS + myrow] = f2bf(p2 * l2e);
    biasB[3 * NPOS + myrow] = f2bf(p3 * l2e);
  }
  bf16x8 a[4];
  #pragma unroll
  for (int kc = 0; kc < 4; kc++)
    #pragma unroll
    for (int e = 0; e < 8; e++) a[kc][e] = (short)f2bf(xv[kc * 8 + e]);

  ushort* st = stg[wv];
  // ---- 4 sections: q | k | v | gate ----
  #pragma unroll
  for (int s4 = 0; s4 < 4; s4++) {
    f32x4 acc[8];
    #pragma unroll
    for (int ntl = 0; ntl < 8; ntl++) {
      f32x4 c = {0.f, 0.f, 0.f, 0.f};
      #pragma unroll
      for (int kc = 0; kc < 4; kc++) {
        bf16x8 b = *(const bf16x8*)(WT + (size_t)(s4 * 128 + ntl * 16 + n) * 128 + kc * 32 + g * 8);
        c = __builtin_amdgcn_mfma_f32_16x16x32_bf16(a[kc], b, c, 0, 0, 0);
      }
      acc[ntl] = c;
    }
    if (s4 == 2) {
      // V: stage transposed [128 hd][24 k-slot]
      #pragma unroll
      for (int ntl = 0; ntl < 8; ntl++) {
        uint2 vp;
        vp.x = (unsigned int)f2bf(acc[ntl][0]) | ((unsigned int)f2bf(acc[ntl][1]) << 16);
        vp.y = (unsigned int)f2bf(acc[ntl][2]) | ((unsigned int)f2bf(acc[ntl][3]) << 16);
        *(uint2*)(&st[(ntl * 16 + n) * 24 + g * 4]) = vp;
      }
      #pragma unroll
      for (int it = 0; it < 4; it++) {
        int c = it * 64 + lane;
        int hd = c >> 1, half = c & 1;
        bf16x8 vv = *(const bf16x8*)(&st[hd * 24 + half * 8]);
        int h = hd >> 5, d = hd & 31;
        *(bf16x8*)(vT + ((size_t)(i * 4 + h) * 32 + d) * 256 + j0b + m0 + half * 8) = vv;
      }
    } else {
      #pragma unroll
      for (int ntl = 0; ntl < 8; ntl++) {
        #pragma unroll
        for (int r = 0; r < 4; r++) {
          float val = acc[ntl][r];
          if (s4 == 3) val = 1.0f / (1.0f + __expf(-(val + bg[ntl * 16 + n])));
          st[(g * 4 + r) * 136 + ntl * 16 + n] = f2bf(val);
        }
      }
      if (s4 == 3) {
        #pragma unroll
        for (int it = 0; it < 4; it++) {
          int c = it * 64 + lane;
          int row = c >> 4, off = (c & 15) * 8;
          *(bf16x8*)(gate + (size_t)(row0 + m0 + row) * 128 + off) =
              *(const bf16x8*)(&st[row * 136 + off]);
        }
      } else {
        ushort* dst = (s4 == 0) ? q : kmat;
        int row = lane >> 2, off = (lane & 3) * 8;
        #pragma unroll
        for (int h = 0; h < 4; h++)
          *(bf16x8*)(dst + ((size_t)(i * 4 + h) * 256 + j0b + m0 + row) * 32 + off) =
              *(const bf16x8*)(&st[row * 136 + h * 32 + off]);
      }
    }
  }
}

// ---------------- K2: fused attention + out-proj + residual ----------------
// grid 512 = (i:256)x(jh:2), 512 thr = 8 waves. Wave wv = (head h=wv&3,
// query-half jjh=wv>>2) runs attention for 64 queries, staging gated ctx into
// a padded LDS tile (stride 136 ushorts breaks the D=128 bank conflict).
// One barrier, then each wave out-projects 16 rows via operand-swapped MFMA
// (A=Wo fragment, B=ctx fragment) -> lane holds 4 consecutive out cols of one
// row -> direct coalesced f32x4 residual-add stores. Kills gctx's 32MB HBM
// round trip and the entire k_out dispatch.
#define PST 40   // P-stage row stride (ushorts; 80B, 16B-aligned)
#define GST 136  // gated-ctx LDS row stride (ushorts; 272B, 16B-aligned, pad +8)
__global__ __launch_bounds__(512, 2) void k_attnout(
    const ushort* __restrict__ q, const ushort* __restrict__ kmat,
    const ushort* __restrict__ vT, const ushort* __restrict__ gate,
    const ushort* __restrict__ biasB, const ushort* __restrict__ WoT,
    const float* __restrict__ bo, const float* __restrict__ in0,
    float* __restrict__ out) {
  __shared__ __align__(16) float stg[8][16 * 36];    // per-wave P/CT staging
  __shared__ __align__(16) ushort gstg[128 * GST];   // gated ctx tile, 34816 B
  int i = blockIdx.x >> 1, jh = blockIdx.x & 1;
  int t = threadIdx.x, wv = t >> 6, lane = t & 63;
  int h = wv & 3, jjh = wv >> 2;
  int n = lane & 15, g = lane >> 4;
  const ushort* qb = q    + (size_t)(i * 4 + h) * 8192;
  const ushort* kb = kmat + (size_t)(i * 4 + h) * 8192;
  const ushort* vb = vT   + (size_t)(i * 4 + h) * 8192;
  const ushort* bb = biasB + (size_t)h * NPOS;
  ushort* Pw = (ushort*)stg[wv];
  float* CT = stg[wv];

  for (int jj = 0; jj < 4; jj++) {
    int j0 = jh * 128 + jjh * 64 + jj * 16;
    // Q as B-operand (col = query), K as A-operand (row = key) -> S^T tiles
    bf16x8 bq = *(const bf16x8*)(qb + (size_t)(j0 + n) * 32 + g * 8);
    f32x4 s[16];
    #pragma unroll
    for (int kt = 0; kt < 16; kt++) {
      uint2 bv = *(const uint2*)(bb + (size_t)(j0 + n) * 256 + kt * 16 + g * 4);
      bf16x8 ak = *(const bf16x8*)(kb + (size_t)(kt * 16 + n) * 32 + g * 8);
      f32x4 c;
      c[0] = lo_bf(bv.x); c[1] = hi_bf(bv.x);
      c[2] = lo_bf(bv.y); c[3] = hi_bf(bv.y);
      s[kt] = __builtin_amdgcn_mfma_f32_16x16x32_bf16(ak, bq, c, 0, 0, 0);
    }
    // softmax: exp2 (log2e pre-folded), no max-sub (scores bounded ~|2|)
    f32x4 a4 = {0.f, 0.f, 0.f, 0.f};
    #pragma unroll
    for (int kt = 0; kt < 16; kt++) {
      #pragma unroll
      for (int r = 0; r < 4; r++) s[kt][r] = EXP2F(s[kt][r]);
      a4 += s[kt];
    }
    float sm = (a4[0] + a4[1]) + (a4[2] + a4[3]);
    sm += __shfl_xor(sm, 16, 64);
    sm += __shfl_xor(sm, 32, 64);
    float inv = RCPF(sm);   // per-lane: this lane's query = n
    // PV interleaved with P staging in 32-key chunks (wave-private LDS,
    // in-order DS pipe => no waits/barriers needed)
    f32x4 ctx0 = {0.f, 0.f, 0.f, 0.f}, ctx1 = {0.f, 0.f, 0.f, 0.f};
    #pragma unroll
    for (int c8 = 0; c8 < 8; c8++) {
      #pragma unroll
      for (int t2 = 0; t2 < 2; t2++) {
        int kt = c8 * 2 + t2;
        uint2 pp;
        pp.x = permpack(s[kt][1] * inv, s[kt][0] * inv);
        pp.y = permpack(s[kt][3] * inv, s[kt][2] * inv);
        *(uint2*)(&Pw[n * PST + t2 * 16 + g * 4]) = pp;   // row=query n, 4 keys
      }
      bf16x8 ap = *(const bf16x8*)(&Pw[n * PST + g * 8]);
      bf16x8 v0 = *(const bf16x8*)(vb + (size_t)n * 256 + c8 * 32 + g * 8);
      bf16x8 v1 = *(const bf16x8*)(vb + (size_t)(16 + n) * 256 + c8 * 32 + g * 8);
      ctx0 = __builtin_amdgcn_mfma_f32_16x16x32_bf16(ap, v0, ctx0, 0, 0, 0);
      ctx1 = __builtin_amdgcn_mfma_f32_16x16x32_bf16(ap, v1, ctx1, 0, 0, 0);
    }
    // ctx stage f32 (stride 36), gate applied on drain into gstg (LDS)
    #pragma unroll
    for (int r = 0; r < 4; r++) {
      CT[(g * 4 + r) * 36 + n] = ctx0[r];
      CT[(g * 4 + r) * 36 + 16 + n] = ctx1[r];
    }
    {
      int row = lane >> 2, part = lane & 3;
      int lrow = jjh * 64 + jj * 16 + row;   // block-local output row 0..127
      size_t o = ((size_t)i * 256 + j0 + row) * 128 + h * 32 + part * 8;
      bf16x8 gt = *(const bf16x8*)(gate + o);
      bf16x8 outp;
      #pragma unroll
      for (int e = 0; e < 8; e++)
        outp[e] = (short)f2bf(CT[row * 36 + part * 8 + e] * bf2f((unsigned short)gt[e]));
      *(bf16x8*)(&gstg[lrow * GST + h * 32 + part * 8]) = outp;
    }
  }
  __syncthreads();
  // ---- out-proj: wave wv -> block-local rows wv*16..+16, all 128 cols ----
  {
    int r0 = wv * 16;
    bf16x8 cfr[4];
    #pragma unroll
    for (int kc = 0; kc < 4; kc++)
      cfr[kc] = *(const bf16x8*)(&gstg[(r0 + n) * GST + kc * 32 + g * 8]);
    size_t rowg = (size_t)i * 256 + jh * 128 + r0 + n;
    #pragma unroll
    for (int ntl = 0; ntl < 8; ntl++) {
      f32x4 acc = {0.f, 0.f, 0.f, 0.f};
      #pragma unroll
      for (int kc = 0; kc < 4; kc++) {
        bf16x8 wo = *(const bf16x8*)(WoT + (size_t)(ntl * 16 + n) * 128 + kc * 32 + g * 8);
        acc = __builtin_amdgcn_mfma_f32_16x16x32_bf16(wo, cfr[kc], acc, 0, 0, 0);
      }
      // D: col=lane&15 -> j-row (r0+n); row=g*4+r -> out col ntl*16+g*4+r
      f32x4 b4 = *(const f32x4*)(bo + ntl * 16 + g * 4);
      size_t o = rowg * 128 + ntl * 16 + g * 4;
      f32x4 r4 = *(const f32x4*)(in0 + o);
      acc[0] += b4[0] + r4[0]; acc[1] += b4[1] + r4[1];
      acc[2] += b4[2] + r4[2]; acc[3] += b4[3] + r4[3];
      *(f32x4*)(out + o) = acc;
    }
  }
}

extern "C" void kernel_launch(void* const* d_in, const int* in_sizes, int n_in,
                              void* d_out, int out_size, void* d_ws, size_t ws_size,
                              hipStream_t stream) {
  const float* in0   = (const float*)d_in[0];
  const float* gamma = (const float*)d_in[1];
  const float* beta  = (const float*)d_in[2];
  const float* Wq    = (const float*)d_in[3];
  const float* Wk    = (const float*)d_in[4];
  const float* Wv    = (const float*)d_in[5];
  const float* Wb    = (const float*)d_in[6];
  const float* Wg    = (const float*)d_in[7];
  const float* bg    = (const float*)d_in[8];
  const float* Wo    = (const float*)d_in[9];
  const float* bo    = (const float*)d_in[10];
  float* out = (float*)d_out;
  char* ws = (char*)d_ws;

  const size_t MB = 1024 * 1024;
  ushort* qbuf  = (ushort*)(ws);              // 16 MB: [ih][j][d]
  ushort* kbuf  = (ushort*)(ws + 16 * MB);    // 16 MB: [ih][k][d]
  ushort* vTbuf = (ushort*)(ws + 32 * MB);    // 16 MB: [ih][d][k]
  ushort* gbuf  = (ushort*)(ws + 48 * MB);    // 16 MB: gate [pos][128]
  ushort* biasB = (ushort*)(ws + 80 * MB);    // 512 KB: [h][j*256+k] * log2e
  ushort* WT    = (ushort*)(ws + 81 * MB);    // 128 KB
  ushort* WoT   = (ushort*)(ws + 81 * MB + 128 * 1024);  // 32 KB

  k_pack   <<<320, 256, 0, stream>>>(Wq, Wk, Wv, Wg, Wo, WT, WoT);
  k_lnproj <<<2048, 128, 0, stream>>>(in0, gamma, beta, Wb, WT, bg,
                                      qbuf, kbuf, vTbuf, gbuf, biasB);
  k_attnout<<<512, 512, 0, stream>>>(qbuf, kbuf, vTbuf, gbuf, biasB,
                                     WoT, bo, in0, out);
}

// Round 4
// 235.170 us; speedup vs baseline: 1.1615x; 1.0327x over previous
//
#include <hip/hip_runtime.h>

#define NPOS 65536   // 256*256

typedef __attribute__((ext_vector_type(8))) short bf16x8;
typedef __attribute__((ext_vector_type(4))) float f32x4;

#if __has_builtin(__builtin_amdgcn_exp2f)
#define EXP2F(x) __builtin_amdgcn_exp2f(x)
#else
#define EXP2F(x) __expf((x) * 0.6931471805599453f)
#endif
#if __has_builtin(__builtin_amdgcn_rcpf)
#define RCPF(x) __builtin_amdgcn_rcpf(x)
#else
#define RCPF(x) (1.0f / (x))
#endif

static __device__ __forceinline__ unsigned short f2bf(float f) {
  union { float f; unsigned int u; } v; v.f = f;
  unsigned int r = v.u + 0x7fffu + ((v.u >> 16) & 1u);
  return (unsigned short)(r >> 16);
}
static __device__ __forceinline__ float bf2f(unsigned short u) {
  union { unsigned int u; float f; } v; v.u = ((unsigned int)u) << 16;
  return v.f;
}
static __device__ __forceinline__ float lo_bf(unsigned int u) {
  union { unsigned int u; float f; } v; v.u = u << 16; return v.f;
}
static __device__ __forceinline__ float hi_bf(unsigned int u) {
  union { unsigned int u; float f; } v; v.u = u & 0xffff0000u; return v.f;
}
// (hi.bf16_trunc << 16) | lo.bf16_trunc  — 1 instruction (v_perm_b32)
static __device__ __forceinline__ unsigned int permpack(float hi, float lo) {
  union { float f; unsigned int u; } a, b;
  a.f = hi; b.f = lo;
#if __has_builtin(__builtin_amdgcn_perm)
  return __builtin_amdgcn_perm(a.u, b.u, 0x07060302u);
#else
  return (a.u & 0xffff0000u) | (b.u >> 16);
#endif
}

// ---------------- K0: pack transposed bf16 weights ----------------
// Wq gets 1/sqrt(32) * log2(e) folded (softmax uses exp2, no max-sub).
__global__ void k_pack(const float* __restrict__ Wq, const float* __restrict__ Wk,
                       const float* __restrict__ Wv, const float* __restrict__ Wg,
                       const float* __restrict__ Wo,
                       ushort* __restrict__ WT, ushort* __restrict__ WoT) {
  int idx = blockIdx.x * blockDim.x + threadIdx.x;
  if (idx < 512 * 128) {
    int n = idx >> 7, k = idx & 127;
    int nn = n & 127;
    float val;
    if (n < 128)      val = Wq[k * 128 + nn] * (0.17677669529663687f * 1.4426950408889634f);
    else if (n < 256) val = Wk[k * 128 + nn];
    else if (n < 384) val = Wv[k * 128 + nn];
    else              val = Wg[k * 128 + nn];
    WT[idx] = f2bf(val);
  } else if (idx < 512 * 128 + 128 * 128) {
    int j = idx - 512 * 128;
    int n = j >> 7, k = j & 127;
    WoT[j] = f2bf(Wo[k * 128 + n]);
  }
}

// ---------------- K1: fused LN + bias + QKVG proj; 128 thr, no barriers -----
// block = 32 rows (grid 2048); wave = 16 rows. bias stored natural [h][pos]*log2e.
// R3: __launch_bounds__(128,2) (VGPR cap 256) + full-section B-prefetch
// b[8][4] (128 VGPR) so all 32 independent WT loads pipeline in one vmcnt
// train instead of ~4-in-flight at the old 64-VGPR budget. Theory: kernel is
// per-wave MLP-starved (VALU 11%, MFMA 4%, HBM 19%, 85% vmcnt stall).
__global__ __launch_bounds__(128, 2) void k_lnproj(
    const float* __restrict__ in, const float* __restrict__ gamma,
    const float* __restrict__ beta, const float* __restrict__ Wb,
    const ushort* __restrict__ WT, const float* __restrict__ bg,
    ushort* __restrict__ q, ushort* __restrict__ kmat, ushort* __restrict__ vT,
    ushort* __restrict__ gate, ushort* __restrict__ biasB) {
  __shared__ __align__(16) ushort stg[2][3072];   // 6 KB per-wave staging
  int t = threadIdx.x, wv = t >> 6, lane = t & 63;
  int n = lane & 15, g = lane >> 4;
  int row0 = blockIdx.x * 32;
  int i = row0 >> 8, j0b = row0 & 255;
  int m0 = wv * 16;
  int myrow = row0 + m0 + n;
  const float* rp = in + (size_t)myrow * 128;

  // ---- LN in registers ----
  float xv[32];
  float s = 0.f, ss = 0.f;
  #pragma unroll
  for (int kc = 0; kc < 4; kc++)
    #pragma unroll
    for (int pr = 0; pr < 2; pr++) {
      float4 v = *(const float4*)(rp + kc * 32 + g * 8 + pr * 4);
      int o = kc * 8 + pr * 4;
      xv[o] = v.x; xv[o+1] = v.y; xv[o+2] = v.z; xv[o+3] = v.w;
      s  += v.x + v.y + v.z + v.w;
      ss += v.x*v.x + v.y*v.y + v.z*v.z + v.w*v.w;
    }
  s  += __shfl_xor(s, 16, 64);  s  += __shfl_xor(s, 32, 64);
  ss += __shfl_xor(ss, 16, 64); ss += __shfl_xor(ss, 32, 64);
  float mu  = s * (1.0f / 128.0f);
  float var = ss * (1.0f / 128.0f) - mu * mu;
  float rs  = rsqrtf(var + 1e-5f);
  float p0 = 0.f, p1 = 0.f, p2 = 0.f, p3 = 0.f;
  #pragma unroll
  for (int kc = 0; kc < 4; kc++)
    #pragma unroll
    for (int pr = 0; pr < 2; pr++) {
      int c0 = kc * 32 + g * 8 + pr * 4;
      float4 g4 = *(const float4*)(gamma + c0);
      float4 b4 = *(const float4*)(beta + c0);
      int o = kc * 8 + pr * 4;
      #pragma unroll
      for (int r = 0; r < 4; r++) {
        float xn = (xv[o + r] - mu) * rs * (&g4.x)[r] + (&b4.x)[r];
        xv[o + r] = xn;
        float4 w = ((const float4*)Wb)[c0 + r];
        p0 += xn * w.x; p1 += xn * w.y; p2 += xn * w.z; p3 += xn * w.w;
      }
    }
  p0 += __shfl_xor(p0, 16, 64); p0 += __shfl_xor(p0, 32, 64);
  p1 += __shfl_xor(p1, 16, 64); p1 += __shfl_xor(p1, 32, 64);
  p2 += __shfl_xor(p2, 16, 64); p2 += __shfl_xor(p2, 32, 64);
  p3 += __shfl_xor(p3, 16, 64); p3 += __shfl_xor(p3, 32, 64);
  if (g == 0) {
    const float l2e = 1.4426950408889634f;
    biasB[0 * NPOS + myrow] = f2bf(p0 * l2e);
    biasB[1 * NPOS + myrow] = f2bf(p1 * l2e);
    biasB[2 * NPOS + myrow] = f2bf(p2 * l2e);
    biasB[3 * NPOS + myrow] = f2bf(p3 * l2e);
  }
  bf16x8 a[4];
  #pragma unroll
  for (int kc = 0; kc < 4; kc++)
    #pragma unroll
    for (int e = 0; e < 8; e++) a[kc][e] = (short)f2bf(xv[kc * 8 + e]);

  ushort* st = stg[wv];
  // ---- 4 sections: q | k | v | gate ----
  #pragma unroll
  for (int s4 = 0; s4 < 4; s4++) {
    // batch-issue ALL 32 B-operand loads for this section (128 VGPRs),
    // then run the 32 MFMAs — one latency exposure instead of ~8.
    bf16x8 b[8][4];
    #pragma unroll
    for (int ntl = 0; ntl < 8; ntl++)
      #pragma unroll
      for (int kc = 0; kc < 4; kc++)
        b[ntl][kc] = *(const bf16x8*)(WT + (size_t)(s4 * 128 + ntl * 16 + n) * 128 + kc * 32 + g * 8);
    f32x4 acc[8];
    #pragma unroll
    for (int ntl = 0; ntl < 8; ntl++) {
      f32x4 c = {0.f, 0.f, 0.f, 0.f};
      #pragma unroll
      for (int kc = 0; kc < 4; kc++)
        c = __builtin_amdgcn_mfma_f32_16x16x32_bf16(a[kc], b[ntl][kc], c, 0, 0, 0);
      acc[ntl] = c;
    }
    if (s4 == 2) {
      // V: stage transposed [128 hd][24 k-slot]
      #pragma unroll
      for (int ntl = 0; ntl < 8; ntl++) {
        uint2 vp;
        vp.x = (unsigned int)f2bf(acc[ntl][0]) | ((unsigned int)f2bf(acc[ntl][1]) << 16);
        vp.y = (unsigned int)f2bf(acc[ntl][2]) | ((unsigned int)f2bf(acc[ntl][3]) << 16);
        *(uint2*)(&st[(ntl * 16 + n) * 24 + g * 4]) = vp;
      }
      #pragma unroll
      for (int it = 0; it < 4; it++) {
        int c = it * 64 + lane;
        int hd = c >> 1, half = c & 1;
        bf16x8 vv = *(const bf16x8*)(&st[hd * 24 + half * 8]);
        int h = hd >> 5, d = hd & 31;
        *(bf16x8*)(vT + ((size_t)(i * 4 + h) * 32 + d) * 256 + j0b + m0 + half * 8) = vv;
      }
    } else {
      #pragma unroll
      for (int ntl = 0; ntl < 8; ntl++) {
        #pragma unroll
        for (int r = 0; r < 4; r++) {
          float val = acc[ntl][r];
          if (s4 == 3) val = 1.0f / (1.0f + __expf(-(val + bg[ntl * 16 + n])));
          st[(g * 4 + r) * 136 + ntl * 16 + n] = f2bf(val);
        }
      }
      if (s4 == 3) {
        #pragma unroll
        for (int it = 0; it < 4; it++) {
          int c = it * 64 + lane;
          int row = c >> 4, off = (c & 15) * 8;
          *(bf16x8*)(gate + (size_t)(row0 + m0 + row) * 128 + off) =
              *(const bf16x8*)(&st[row * 136 + off]);
        }
      } else {
        ushort* dst = (s4 == 0) ? q : kmat;
        int row = lane >> 2, off = (lane & 3) * 8;
        #pragma unroll
        for (int h = 0; h < 4; h++)
          *(bf16x8*)(dst + ((size_t)(i * 4 + h) * 256 + j0b + m0 + row) * 32 + off) =
              *(const bf16x8*)(&st[row * 136 + h * 32 + off]);
      }
    }
  }
}

// ---------------- K2: fused attention + out-proj + residual ----------------
// grid 512 = (i:256)x(jh:2), 512 thr = 8 waves. Wave wv = (head h=wv&3,
// query-half jjh=wv>>2) runs attention for 64 queries, staging gated ctx into
// a padded LDS tile (stride 136 ushorts breaks the D=128 bank conflict).
// One barrier, then each wave out-projects 16 rows via operand-swapped MFMA
// (A=Wo fragment, B=ctx fragment) -> lane holds 4 consecutive out cols of one
// row -> direct coalesced f32x4 residual-add stores. Kills gctx's 32MB HBM
// round trip and the entire k_out dispatch.
#define PST 40   // P-stage row stride (ushorts; 80B, 16B-aligned)
#define GST 136  // gated-ctx LDS row stride (ushorts; 272B, 16B-aligned, pad +8)
__global__ __launch_bounds__(512, 2) void k_attnout(
    const ushort* __restrict__ q, const ushort* __restrict__ kmat,
    const ushort* __restrict__ vT, const ushort* __restrict__ gate,
    const ushort* __restrict__ biasB, const ushort* __restrict__ WoT,
    const float* __restrict__ bo, const float* __restrict__ in0,
    float* __restrict__ out) {
  __shared__ __align__(16) float stg[8][16 * 36];    // per-wave P/CT staging
  __shared__ __align__(16) ushort gstg[128 * GST];   // gated ctx tile, 34816 B
  int i = blockIdx.x >> 1, jh = blockIdx.x & 1;
  int t = threadIdx.x, wv = t >> 6, lane = t & 63;
  int h = wv & 3, jjh = wv >> 2;
  int n = lane & 15, g = lane >> 4;
  const ushort* qb = q    + (size_t)(i * 4 + h) * 8192;
  const ushort* kb = kmat + (size_t)(i * 4 + h) * 8192;
  const ushort* vb = vT   + (size_t)(i * 4 + h) * 8192;
  const ushort* bb = biasB + (size_t)h * NPOS;
  ushort* Pw = (ushort*)stg[wv];
  float* CT = stg[wv];

  for (int jj = 0; jj < 4; jj++) {
    int j0 = jh * 128 + jjh * 64 + jj * 16;
    // Q as B-operand (col = query), K as A-operand (row = key) -> S^T tiles
    bf16x8 bq = *(const bf16x8*)(qb + (size_t)(j0 + n) * 32 + g * 8);
    f32x4 s[16];
    #pragma unroll
    for (int kt = 0; kt < 16; kt++) {
      uint2 bv = *(const uint2*)(bb + (size_t)(j0 + n) * 256 + kt * 16 + g * 4);
      bf16x8 ak = *(const bf16x8*)(kb + (size_t)(kt * 16 + n) * 32 + g * 8);
      f32x4 c;
      c[0] = lo_bf(bv.x); c[1] = hi_bf(bv.x);
      c[2] = lo_bf(bv.y); c[3] = hi_bf(bv.y);
      s[kt] = __builtin_amdgcn_mfma_f32_16x16x32_bf16(ak, bq, c, 0, 0, 0);
    }
    // softmax: exp2 (log2e pre-folded), no max-sub (scores bounded ~|2|)
    f32x4 a4 = {0.f, 0.f, 0.f, 0.f};
    #pragma unroll
    for (int kt = 0; kt < 16; kt++) {
      #pragma unroll
      for (int r = 0; r < 4; r++) s[kt][r] = EXP2F(s[kt][r]);
      a4 += s[kt];
    }
    float sm = (a4[0] + a4[1]) + (a4[2] + a4[3]);
    sm += __shfl_xor(sm, 16, 64);
    sm += __shfl_xor(sm, 32, 64);
    float inv = RCPF(sm);   // per-lane: this lane's query = n
    // PV interleaved with P staging in 32-key chunks (wave-private LDS,
    // in-order DS pipe => no waits/barriers needed)
    f32x4 ctx0 = {0.f, 0.f, 0.f, 0.f}, ctx1 = {0.f, 0.f, 0.f, 0.f};
    #pragma unroll
    for (int c8 = 0; c8 < 8; c8++) {
      #pragma unroll
      for (int t2 = 0; t2 < 2; t2++) {
        int kt = c8 * 2 + t2;
        uint2 pp;
        pp.x = permpack(s[kt][1] * inv, s[kt][0] * inv);
        pp.y = permpack(s[kt][3] * inv, s[kt][2] * inv);
        *(uint2*)(&Pw[n * PST + t2 * 16 + g * 4]) = pp;   // row=query n, 4 keys
      }
      bf16x8 ap = *(const bf16x8*)(&Pw[n * PST + g * 8]);
      bf16x8 v0 = *(const bf16x8*)(vb + (size_t)n * 256 + c8 * 32 + g * 8);
      bf16x8 v1 = *(const bf16x8*)(vb + (size_t)(16 + n) * 256 + c8 * 32 + g * 8);
      ctx0 = __builtin_amdgcn_mfma_f32_16x16x32_bf16(ap, v0, ctx0, 0, 0, 0);
      ctx1 = __builtin_amdgcn_mfma_f32_16x16x32_bf16(ap, v1, ctx1, 0, 0, 0);
    }
    // ctx stage f32 (stride 36), gate applied on drain into gstg (LDS)
    #pragma unroll
    for (int r = 0; r < 4; r++) {
      CT[(g * 4 + r) * 36 + n] = ctx0[r];
      CT[(g * 4 + r) * 36 + 16 + n] = ctx1[r];
    }
    {
      int row = lane >> 2, part = lane & 3;
      int lrow = jjh * 64 + jj * 16 + row;   // block-local output row 0..127
      size_t o = ((size_t)i * 256 + j0 + row) * 128 + h * 32 + part * 8;
      bf16x8 gt = *(const bf16x8*)(gate + o);
      bf16x8 outp;
      #pragma unroll
      for (int e = 0; e < 8; e++)
        outp[e] = (short)f2bf(CT[row * 36 + part * 8 + e] * bf2f((unsigned short)gt[e]));
      *(bf16x8*)(&gstg[lrow * GST + h * 32 + part * 8]) = outp;
    }
  }
  __syncthreads();
  // ---- out-proj: wave wv -> block-local rows wv*16..+16, all 128 cols ----
  {
    int r0 = wv * 16;
    bf16x8 cfr[4];
    #pragma unroll
    for (int kc = 0; kc < 4; kc++)
      cfr[kc] = *(const bf16x8*)(&gstg[(r0 + n) * GST + kc * 32 + g * 8]);
    size_t rowg = (size_t)i * 256 + jh * 128 + r0 + n;
    #pragma unroll
    for (int ntl = 0; ntl < 8; ntl++) {
      f32x4 acc = {0.f, 0.f, 0.f, 0.f};
      #pragma unroll
      for (int kc = 0; kc < 4; kc++) {
        bf16x8 wo = *(const bf16x8*)(WoT + (size_t)(ntl * 16 + n) * 128 + kc * 32 + g * 8);
        acc = __builtin_amdgcn_mfma_f32_16x16x32_bf16(wo, cfr[kc], acc, 0, 0, 0);
      }
      // D: col=lane&15 -> j-row (r0+n); row=g*4+r -> out col ntl*16+g*4+r
      f32x4 b4 = *(const f32x4*)(bo + ntl * 16 + g * 4);
      size_t o = rowg * 128 + ntl * 16 + g * 4;
      f32x4 r4 = *(const f32x4*)(in0 + o);
      acc[0] += b4[0] + r4[0]; acc[1] += b4[1] + r4[1];
      acc[2] += b4[2] + r4[2]; acc[3] += b4[3] + r4[3];
      *(f32x4*)(out + o) = acc;
    }
  }
}

extern "C" void kernel_launch(void* const* d_in, const int* in_sizes, int n_in,
                              void* d_out, int out_size, void* d_ws, size_t ws_size,
                              hipStream_t stream) {
  const float* in0   = (const float*)d_in[0];
  const float* gamma = (const float*)d_in[1];
  const float* beta  = (const float*)d_in[2];
  const float* Wq    = (const float*)d_in[3];
  const float* Wk    = (const float*)d_in[4];
  const float* Wv    = (const float*)d_in[5];
  const float* Wb    = (const float*)d_in[6];
  const float* Wg    = (const float*)d_in[7];
  const float* bg    = (const float*)d_in[8];
  const float* Wo    = (const float*)d_in[9];
  const float* bo    = (const float*)d_in[10];
  float* out = (float*)d_out;
  char* ws = (char*)d_ws;

  const size_t MB = 1024 * 1024;
  ushort* qbuf  = (ushort*)(ws);              // 16 MB: [ih][j][d]
  ushort* kbuf  = (ushort*)(ws + 16 * MB);    // 16 MB: [ih][k][d]
  ushort* vTbuf = (ushort*)(ws + 32 * MB);    // 16 MB: [ih][d][k]
  ushort* gbuf  = (ushort*)(ws + 48 * MB);    // 16 MB: gate [pos][128]
  ushort* biasB = (ushort*)(ws + 80 * MB);    // 512 KB: [h][j*256+k] * log2e
  ushort* WT    = (ushort*)(ws + 81 * MB);    // 128 KB
  ushort* WoT   = (ushort*)(ws + 81 * MB + 128 * 1024);  // 32 KB

  k_pack   <<<320, 256, 0, stream>>>(Wq, Wk, Wv, Wg, Wo, WT, WoT);
  k_lnproj <<<2048, 128, 0, stream>>>(in0, gamma, beta, Wb, WT, bg,
                                      qbuf, kbuf, vTbuf, gbuf, biasB);
  k_attnout<<<512, 512, 0, stream>>>(qbuf, kbuf, vTbuf, gbuf, biasB,
                                     WoT, bo, in0, out);
}

// Round 5
// 220.136 us; speedup vs baseline: 1.2408x; 1.0683x over previous
//
#include <hip/hip_runtime.h>

#define NPOS 65536   // 256*256

typedef __attribute__((ext_vector_type(8))) short bf16x8;
typedef __attribute__((ext_vector_type(4))) float f32x4;

#if __has_builtin(__builtin_amdgcn_exp2f)
#define EXP2F(x) __builtin_amdgcn_exp2f(x)
#else
#define EXP2F(x) __expf((x) * 0.6931471805599453f)
#endif
#if __has_builtin(__builtin_amdgcn_rcpf)
#define RCPF(x) __builtin_amdgcn_rcpf(x)
#else
#define RCPF(x) (1.0f / (x))
#endif

static __device__ __forceinline__ unsigned short f2bf(float f) {
  union { float f; unsigned int u; } v; v.f = f;
  unsigned int r = v.u + 0x7fffu + ((v.u >> 16) & 1u);
  return (unsigned short)(r >> 16);
}
static __device__ __forceinline__ float lo_bf(unsigned int u) {
  union { unsigned int u; float f; } v; v.u = u << 16; return v.f;
}
static __device__ __forceinline__ float hi_bf(unsigned int u) {
  union { unsigned int u; float f; } v; v.u = u & 0xffff0000u; return v.f;
}
// (hi.bf16_trunc << 16) | lo.bf16_trunc  — 1 instruction (v_perm_b32)
static __device__ __forceinline__ unsigned int permpack(float hi, float lo) {
  union { float f; unsigned int u; } a, b;
  a.f = hi; b.f = lo;
#if __has_builtin(__builtin_amdgcn_perm)
  return __builtin_amdgcn_perm(a.u, b.u, 0x07060302u);
#else
  return (a.u & 0xffff0000u) | (b.u >> 16);
#endif
}

// ---------------- K0: pack transposed bf16 weights ----------------
// Wq gets 1/sqrt(32) * log2(e) folded (softmax uses exp2, no max-sub).
__global__ void k_pack(const float* __restrict__ Wq, const float* __restrict__ Wk,
                       const float* __restrict__ Wv, const float* __restrict__ Wg,
                       const float* __restrict__ Wo,
                       ushort* __restrict__ WT, ushort* __restrict__ WoT) {
  int idx = blockIdx.x * blockDim.x + threadIdx.x;
  if (idx < 512 * 128) {
    int n = idx >> 7, k = idx & 127;
    int nn = n & 127;
    float val;
    if (n < 128)      val = Wq[k * 128 + nn] * (0.17677669529663687f * 1.4426950408889634f);
    else if (n < 256) val = Wk[k * 128 + nn];
    else if (n < 384) val = Wv[k * 128 + nn];
    else              val = Wg[k * 128 + nn];
    WT[idx] = f2bf(val);
  } else if (idx < 512 * 128 + 128 * 128) {
    int j = idx - 512 * 128;
    int n = j >> 7, k = j & 127;
    WoT[j] = f2bf(Wo[k * 128 + n]);
  }
}

// ---------------- K1: LN + Wb bias projection only ----------------
// biasB[h][pos] = (LN(x[pos]) . Wb[:,h]) * log2e. Pure memory-bound (~34MB read).
__global__ __launch_bounds__(128, 4) void k_lnbias(
    const float* __restrict__ in, const float* __restrict__ gamma,
    const float* __restrict__ beta, const float* __restrict__ Wb,
    ushort* __restrict__ biasB) {
  int t = threadIdx.x, wv = t >> 6, lane = t & 63;
  int n = lane & 15, g = lane >> 4;
  int myrow = blockIdx.x * 32 + wv * 16 + n;
  const float* rp = in + (size_t)myrow * 128;

  float xv[32];
  float sm = 0.f, ssm = 0.f;
  #pragma unroll
  for (int kc = 0; kc < 4; kc++)
    #pragma unroll
    for (int pr = 0; pr < 2; pr++) {
      float4 v = *(const float4*)(rp + kc * 32 + g * 8 + pr * 4);
      int o = kc * 8 + pr * 4;
      xv[o] = v.x; xv[o+1] = v.y; xv[o+2] = v.z; xv[o+3] = v.w;
      sm  += v.x + v.y + v.z + v.w;
      ssm += v.x*v.x + v.y*v.y + v.z*v.z + v.w*v.w;
    }
  sm  += __shfl_xor(sm, 16, 64);  sm  += __shfl_xor(sm, 32, 64);
  ssm += __shfl_xor(ssm, 16, 64); ssm += __shfl_xor(ssm, 32, 64);
  float mu  = sm * (1.0f / 128.0f);
  float var = ssm * (1.0f / 128.0f) - mu * mu;
  float rs  = rsqrtf(var + 1e-5f);
  float p0 = 0.f, p1 = 0.f, p2 = 0.f, p3 = 0.f;
  #pragma unroll
  for (int kc = 0; kc < 4; kc++)
    #pragma unroll
    for (int pr = 0; pr < 2; pr++) {
      int c0 = kc * 32 + g * 8 + pr * 4;
      float4 g4 = *(const float4*)(gamma + c0);
      float4 b4 = *(const float4*)(beta + c0);
      int o = kc * 8 + pr * 4;
      #pragma unroll
      for (int r = 0; r < 4; r++) {
        float xn = (xv[o + r] - mu) * rs * (&g4.x)[r] + (&b4.x)[r];
        float4 w = ((const float4*)Wb)[c0 + r];
        p0 += xn * w.x; p1 += xn * w.y; p2 += xn * w.z; p3 += xn * w.w;
      }
    }
  p0 += __shfl_xor(p0, 16, 64); p0 += __shfl_xor(p0, 32, 64);
  p1 += __shfl_xor(p1, 16, 64); p1 += __shfl_xor(p1, 32, 64);
  p2 += __shfl_xor(p2, 16, 64); p2 += __shfl_xor(p2, 32, 64);
  p3 += __shfl_xor(p3, 16, 64); p3 += __shfl_xor(p3, 32, 64);
  if (g == 0) {
    const float l2e = 1.4426950408889634f;
    biasB[0 * NPOS + myrow] = f2bf(p0 * l2e);
    biasB[1 * NPOS + myrow] = f2bf(p1 * l2e);
    biasB[2 * NPOS + myrow] = f2bf(p2 * l2e);
    biasB[3 * NPOS + myrow] = f2bf(p3 * l2e);
  }
}

// ---------------- K2: fused LN + head-slice proj + attention + gate --------
// grid 1024 = (i:256)x(h:4), 512 thr = 8 waves. Wave wv owns rows wv*32..+32
// of row-block i: LN (2x16-row chunks) -> Q/K/V/gate proj for head h's 32-dim
// slice (K->LDS[256][40], V^T->LDS[32][264], Q->wave LDS, gate in regs).
// One barrier, then attention (same verified S^T/softmax/PV code) on
// LDS-resident K/V^T. Gate lane-mapping == PV output lane-mapping -> gate
// applied in registers, gctx written straight to HBM. Deletes k_lnproj and
// the 64MB q/k/vT/gate round trip.
#define KS 40    // Klds row stride (ushorts; 80B: b128-aligned, 2-way banks)
#define VS 264   // VTlds row stride (ushorts; keys 256 + 8 pad)
#define QS 40    // qstg row stride
#define PST 40   // P-stage row stride
__global__ __launch_bounds__(512, 2) void k_attn2(
    const float* __restrict__ in, const float* __restrict__ gamma,
    const float* __restrict__ beta, const ushort* __restrict__ WT,
    const float* __restrict__ bg, const ushort* __restrict__ biasB,
    ushort* __restrict__ gctx) {
  __shared__ __align__(16) ushort Klds[256 * KS];    // 20480 B
  __shared__ __align__(16) ushort VTlds[32 * VS];    // 16896 B
  __shared__ __align__(16) ushort qstg[8][32 * QS];  // 20480 B
  __shared__ __align__(16) ushort pstg[8][16 * PST]; // 10240 B
  int i = blockIdx.x >> 2, h = blockIdx.x & 3;
  int t = threadIdx.x, wv = t >> 6, lane = t & 63;
  int n = lane & 15, g = lane >> 4;
  int r0 = wv * 32;

  // ---- phase A: LN for the wave's 32 rows (2 chunks of 16) ----
  bf16x8 a[2][4];
  #pragma unroll
  for (int c = 0; c < 2; c++) {
    const float* rp = in + ((size_t)i * 256 + r0 + c * 16 + n) * 128;
    float xv[32];
    float sm = 0.f, ssm = 0.f;
    #pragma unroll
    for (int kc = 0; kc < 4; kc++)
      #pragma unroll
      for (int pr = 0; pr < 2; pr++) {
        float4 v = *(const float4*)(rp + kc * 32 + g * 8 + pr * 4);
        int o = kc * 8 + pr * 4;
        xv[o] = v.x; xv[o+1] = v.y; xv[o+2] = v.z; xv[o+3] = v.w;
        sm  += v.x + v.y + v.z + v.w;
        ssm += v.x*v.x + v.y*v.y + v.z*v.z + v.w*v.w;
      }
    sm  += __shfl_xor(sm, 16, 64);  sm  += __shfl_xor(sm, 32, 64);
    ssm += __shfl_xor(ssm, 16, 64); ssm += __shfl_xor(ssm, 32, 64);
    float mu  = sm * (1.0f / 128.0f);
    float var = ssm * (1.0f / 128.0f) - mu * mu;
    float rs  = rsqrtf(var + 1e-5f);
    #pragma unroll
    for (int kc = 0; kc < 4; kc++)
      #pragma unroll
      for (int pr = 0; pr < 2; pr++) {
        int c0 = kc * 32 + g * 8 + pr * 4;
        float4 g4 = *(const float4*)(gamma + c0);
        float4 b4 = *(const float4*)(beta + c0);
        int o = kc * 8 + pr * 4;
        #pragma unroll
        for (int r = 0; r < 4; r++)
          xv[o + r] = (xv[o + r] - mu) * rs * (&g4.x)[r] + (&b4.x)[r];
      }
    #pragma unroll
    for (int kc = 0; kc < 4; kc++)
      #pragma unroll
      for (int e = 0; e < 8; e++) a[c][kc][e] = (short)f2bf(xv[kc * 8 + e]);
  }

  // ---- phase A2: 4 head-slice projections (32 cols each) ----
  f32x4 gs[2][2];   // gate (sigmoid applied), lane-mapped same as PV output
  #pragma unroll
  for (int sect = 0; sect < 4; sect++) {
    bf16x8 b[2][4];
    #pragma unroll
    for (int ntl = 0; ntl < 2; ntl++)
      #pragma unroll
      for (int kc = 0; kc < 4; kc++)
        b[ntl][kc] = *(const bf16x8*)(WT + (size_t)(sect * 128 + h * 32 + ntl * 16 + n) * 128 + kc * 32 + g * 8);
    #pragma unroll
    for (int c = 0; c < 2; c++) {
      f32x4 acc[2];
      #pragma unroll
      for (int ntl = 0; ntl < 2; ntl++) {
        f32x4 cc = {0.f, 0.f, 0.f, 0.f};
        #pragma unroll
        for (int kc = 0; kc < 4; kc++)
          cc = __builtin_amdgcn_mfma_f32_16x16x32_bf16(a[c][kc], b[ntl][kc], cc, 0, 0, 0);
        acc[ntl] = cc;
      }
      // acc[ntl][r] = proj[row r0+c*16+g*4+r][dim ntl*16+n] (head-local dim)
      if (sect == 0) {          // Q -> wave-private LDS [query][dim]
        #pragma unroll
        for (int ntl = 0; ntl < 2; ntl++)
          #pragma unroll
          for (int r = 0; r < 4; r++)
            qstg[wv][(c * 16 + g * 4 + r) * QS + ntl * 16 + n] = f2bf(acc[ntl][r]);
      } else if (sect == 1) {   // K -> shared LDS [key][dim]
        #pragma unroll
        for (int ntl = 0; ntl < 2; ntl++)
          #pragma unroll
          for (int r = 0; r < 4; r++)
            Klds[(r0 + c * 16 + g * 4 + r) * KS + ntl * 16 + n] = f2bf(acc[ntl][r]);
      } else if (sect == 2) {   // V -> shared LDS transposed [dim][key]
        #pragma unroll
        for (int ntl = 0; ntl < 2; ntl++) {
          uint2 vp;
          vp.x = (unsigned int)f2bf(acc[ntl][0]) | ((unsigned int)f2bf(acc[ntl][1]) << 16);
          vp.y = (unsigned int)f2bf(acc[ntl][2]) | ((unsigned int)f2bf(acc[ntl][3]) << 16);
          *(uint2*)(&VTlds[(ntl * 16 + n) * VS + r0 + c * 16 + g * 4]) = vp;
        }
      } else {                  // gate: keep in registers
        #pragma unroll
        for (int ntl = 0; ntl < 2; ntl++)
          #pragma unroll
          for (int r = 0; r < 4; r++)
            gs[c][ntl][r] = 1.0f / (1.0f + __expf(-(acc[ntl][r] + bg[h * 32 + ntl * 16 + n])));
      }
    }
  }
  __syncthreads();

  // ---- phase B: attention for the wave's 32 queries (2 tiles of 16) ----
  const ushort* bb = biasB + (size_t)h * NPOS;
  ushort* Pw = pstg[wv];
  #pragma unroll
  for (int tt = 0; tt < 2; tt++) {
    int j0 = r0 + tt * 16;
    bf16x8 bq = *(const bf16x8*)(&qstg[wv][(tt * 16 + n) * QS + g * 8]);
    f32x4 s[16];
    #pragma unroll
    for (int kt = 0; kt < 16; kt++) {
      uint2 bv = *(const uint2*)(bb + (size_t)(j0 + n) * 256 + kt * 16 + g * 4);
      bf16x8 ak = *(const bf16x8*)(&Klds[(kt * 16 + n) * KS + g * 8]);
      f32x4 cc;
      cc[0] = lo_bf(bv.x); cc[1] = hi_bf(bv.x);
      cc[2] = lo_bf(bv.y); cc[3] = hi_bf(bv.y);
      s[kt] = __builtin_amdgcn_mfma_f32_16x16x32_bf16(ak, bq, cc, 0, 0, 0);
    }
    // softmax: exp2 (log2e pre-folded), no max-sub (scores bounded ~|2|)
    f32x4 a4 = {0.f, 0.f, 0.f, 0.f};
    #pragma unroll
    for (int kt = 0; kt < 16; kt++) {
      #pragma unroll
      for (int r = 0; r < 4; r++) s[kt][r] = EXP2F(s[kt][r]);
      a4 += s[kt];
    }
    float smm = (a4[0] + a4[1]) + (a4[2] + a4[3]);
    smm += __shfl_xor(smm, 16, 64);
    smm += __shfl_xor(smm, 32, 64);
    float inv = RCPF(smm);
    f32x4 ctx0 = {0.f, 0.f, 0.f, 0.f}, ctx1 = {0.f, 0.f, 0.f, 0.f};
    #pragma unroll
    for (int c8 = 0; c8 < 8; c8++) {
      #pragma unroll
      for (int t2 = 0; t2 < 2; t2++) {
        int kt = c8 * 2 + t2;
        uint2 pp;
        pp.x = permpack(s[kt][1] * inv, s[kt][0] * inv);
        pp.y = permpack(s[kt][3] * inv, s[kt][2] * inv);
        *(uint2*)(&Pw[n * PST + t2 * 16 + g * 4]) = pp;
      }
      bf16x8 ap = *(const bf16x8*)(&Pw[n * PST + g * 8]);
      bf16x8 v0 = *(const bf16x8*)(&VTlds[(size_t)n * VS + c8 * 32 + g * 8]);
      bf16x8 v1 = *(const bf16x8*)(&VTlds[(size_t)(16 + n) * VS + c8 * 32 + g * 8]);
      ctx0 = __builtin_amdgcn_mfma_f32_16x16x32_bf16(ap, v0, ctx0, 0, 0, 0);
      ctx1 = __builtin_amdgcn_mfma_f32_16x16x32_bf16(ap, v1, ctx1, 0, 0, 0);
    }
    // gate in registers (identical lane mapping), direct global store
    #pragma unroll
    for (int r = 0; r < 4; r++) {
      size_t pos = (size_t)i * 256 + j0 + g * 4 + r;
      gctx[pos * 128 + h * 32 + n]      = f2bf(ctx0[r] * gs[tt][0][r]);
      gctx[pos * 128 + h * 32 + 16 + n] = f2bf(ctx1[r] * gs[tt][1][r]);
    }
  }
}

// ---------------- K3: out-proj + bias + residual (R1-verified) ------------
__global__ __launch_bounds__(128, 4) void k_out(
    const ushort* __restrict__ gctx, const ushort* __restrict__ WoT,
    const float* __restrict__ bo, const float* __restrict__ in0,
    float* __restrict__ out) {
  __shared__ __align__(16) float CT[16 * 132];   // 8448B
  int t = threadIdx.x, wv = t >> 6, lane = t & 63;
  int n = lane & 15, g = lane >> 4;
  int row0 = blockIdx.x * 16;
  bf16x8 a[4];
  #pragma unroll
  for (int kc = 0; kc < 4; kc++)
    a[kc] = *(const bf16x8*)(gctx + (size_t)(row0 + n) * 128 + kc * 32 + g * 8);
  #pragma unroll
  for (int ntl2 = 0; ntl2 < 4; ntl2++) {
    int ntl = wv * 4 + ntl2;
    f32x4 acc = {0.f, 0.f, 0.f, 0.f};
    #pragma unroll
    for (int kc = 0; kc < 4; kc++) {
      bf16x8 b = *(const bf16x8*)(WoT + (size_t)(ntl * 16 + n) * 128 + kc * 32 + g * 8);
      acc = __builtin_amdgcn_mfma_f32_16x16x32_bf16(a[kc], b, acc, 0, 0, 0);
    }
    float bov = bo[ntl * 16 + n];
    #pragma unroll
    for (int r = 0; r < 4; r++)
      CT[(g * 4 + r) * 132 + ntl * 16 + n] = acc[r] + bov;
  }
  __syncthreads();
  #pragma unroll
  for (int it = 0; it < 4; it++) {
    int c = it * 128 + t;
    int row = c >> 5, off = (c & 31) * 4;
    f32x4 v = *(const f32x4*)(&CT[row * 132 + off]);
    size_t o = (size_t)(row0 + row) * 128 + off;
    f32x4 r4 = *(const f32x4*)(in0 + o);
    v[0] += r4[0]; v[1] += r4[1]; v[2] += r4[2]; v[3] += r4[3];
    *(f32x4*)(out + o) = v;
  }
}

extern "C" void kernel_launch(void* const* d_in, const int* in_sizes, int n_in,
                              void* d_out, int out_size, void* d_ws, size_t ws_size,
                              hipStream_t stream) {
  const float* in0   = (const float*)d_in[0];
  const float* gamma = (const float*)d_in[1];
  const float* beta  = (const float*)d_in[2];
  const float* Wq    = (const float*)d_in[3];
  const float* Wk    = (const float*)d_in[4];
  const float* Wv    = (const float*)d_in[5];
  const float* Wb    = (const float*)d_in[6];
  const float* Wg    = (const float*)d_in[7];
  const float* bg    = (const float*)d_in[8];
  const float* Wo    = (const float*)d_in[9];
  const float* bo    = (const float*)d_in[10];
  float* out = (float*)d_out;
  char* ws = (char*)d_ws;

  const size_t MB = 1024 * 1024;
  ushort* gctx  = (ushort*)(ws);              // 16 MB: [pos][128]
  ushort* biasB = (ushort*)(ws + 16 * MB);    // 512 KB: [h][j*256+k] * log2e
  ushort* WT    = (ushort*)(ws + 17 * MB);    // 128 KB
  ushort* WoT   = (ushort*)(ws + 17 * MB + 128 * 1024);  // 32 KB

  k_pack  <<<320, 256, 0, stream>>>(Wq, Wk, Wv, Wg, Wo, WT, WoT);
  k_lnbias<<<2048, 128, 0, stream>>>(in0, gamma, beta, Wb, biasB);
  k_attn2 <<<1024, 512, 0, stream>>>(in0, gamma, beta, WT, bg, biasB, gctx);
  k_out   <<<4096, 128, 0, stream>>>(gctx, WoT, bo, in0, out);
}

// Round 6
// 208.661 us; speedup vs baseline: 1.3091x; 1.0550x over previous
//
#include <hip/hip_runtime.h>

#define NPOS 65536   // 256*256

typedef __attribute__((ext_vector_type(8))) short bf16x8;
typedef __attribute__((ext_vector_type(4))) float f32x4;

#if __has_builtin(__builtin_amdgcn_exp2f)
#define EXP2F(x) __builtin_amdgcn_exp2f(x)
#else
#define EXP2F(x) __expf((x) * 0.6931471805599453f)
#endif
#if __has_builtin(__builtin_amdgcn_rcpf)
#define RCPF(x) __builtin_amdgcn_rcpf(x)
#else
#define RCPF(x) (1.0f / (x))
#endif

static __device__ __forceinline__ unsigned short f2bf(float f) {
  union { float f; unsigned int u; } v; v.f = f;
  unsigned int r = v.u + 0x7fffu + ((v.u >> 16) & 1u);
  return (unsigned short)(r >> 16);
}
static __device__ __forceinline__ unsigned int pack2(float a, float b) {
  return (unsigned int)f2bf(a) | ((unsigned int)f2bf(b) << 16);
}
static __device__ __forceinline__ float lo_bf(unsigned int u) {
  union { unsigned int u; float f; } v; v.u = u << 16; return v.f;
}
static __device__ __forceinline__ float hi_bf(unsigned int u) {
  union { unsigned int u; float f; } v; v.u = u & 0xffff0000u; return v.f;
}
// (hi.bf16_trunc << 16) | lo.bf16_trunc  — 1 instruction (v_perm_b32)
static __device__ __forceinline__ unsigned int permpack(float hi, float lo) {
  union { float f; unsigned int u; } a, b;
  a.f = hi; b.f = lo;
#if __has_builtin(__builtin_amdgcn_perm)
  return __builtin_amdgcn_perm(a.u, b.u, 0x07060302u);
#else
  return (a.u & 0xffff0000u) | (b.u >> 16);
#endif
}

// ---------------- K0: pack transposed bf16 weights ----------------
// Wq gets 1/sqrt(32) * log2(e) folded (softmax uses exp2, no max-sub).
__global__ void k_pack(const float* __restrict__ Wq, const float* __restrict__ Wk,
                       const float* __restrict__ Wv, const float* __restrict__ Wg,
                       const float* __restrict__ Wo,
                       ushort* __restrict__ WT, ushort* __restrict__ WoT) {
  int idx = blockIdx.x * blockDim.x + threadIdx.x;
  if (idx < 512 * 128) {
    int n = idx >> 7, k = idx & 127;
    int nn = n & 127;
    float val;
    if (n < 128)      val = Wq[k * 128 + nn] * (0.17677669529663687f * 1.4426950408889634f);
    else if (n < 256) val = Wk[k * 128 + nn];
    else if (n < 384) val = Wv[k * 128 + nn];
    else              val = Wg[k * 128 + nn];
    WT[idx] = f2bf(val);
  } else if (idx < 512 * 128 + 128 * 128) {
    int j = idx - 512 * 128;
    int n = j >> 7, k = j & 127;
    WoT[j] = f2bf(Wo[k * 128 + n]);
  }
}

// ---------------- K1: LN (store bf16 x_ln) + Wb bias projection ----------
// R5: LN computed ONCE here for all 65536 positions; x_ln stored bf16 so
// k_attn2 loads MFMA a-frags directly (deletes its 4x-redundant LN).
__global__ __launch_bounds__(128, 4) void k_ln(
    const float* __restrict__ in, const float* __restrict__ gamma,
    const float* __restrict__ beta, const float* __restrict__ Wb,
    ushort* __restrict__ xln, ushort* __restrict__ biasB) {
  int t = threadIdx.x, wv = t >> 6, lane = t & 63;
  int n = lane & 15, g = lane >> 4;
  int myrow = blockIdx.x * 32 + wv * 16 + n;
  const float* rp = in + (size_t)myrow * 128;

  float xv[32];
  float sm = 0.f, ssm = 0.f;
  #pragma unroll
  for (int kc = 0; kc < 4; kc++)
    #pragma unroll
    for (int pr = 0; pr < 2; pr++) {
      float4 v = *(const float4*)(rp + kc * 32 + g * 8 + pr * 4);
      int o = kc * 8 + pr * 4;
      xv[o] = v.x; xv[o+1] = v.y; xv[o+2] = v.z; xv[o+3] = v.w;
      sm  += v.x + v.y + v.z + v.w;
      ssm += v.x*v.x + v.y*v.y + v.z*v.z + v.w*v.w;
    }
  sm  += __shfl_xor(sm, 16, 64);  sm  += __shfl_xor(sm, 32, 64);
  ssm += __shfl_xor(ssm, 16, 64); ssm += __shfl_xor(ssm, 32, 64);
  float mu  = sm * (1.0f / 128.0f);
  float var = ssm * (1.0f / 128.0f) - mu * mu;
  float rs  = rsqrtf(var + 1e-5f);
  float p0 = 0.f, p1 = 0.f, p2 = 0.f, p3 = 0.f;
  #pragma unroll
  for (int kc = 0; kc < 4; kc++)
    #pragma unroll
    for (int pr = 0; pr < 2; pr++) {
      int c0 = kc * 32 + g * 8 + pr * 4;
      float4 g4 = *(const float4*)(gamma + c0);
      float4 b4 = *(const float4*)(beta + c0);
      int o = kc * 8 + pr * 4;
      #pragma unroll
      for (int r = 0; r < 4; r++) {
        float xn = (xv[o + r] - mu) * rs * (&g4.x)[r] + (&b4.x)[r];
        xv[o + r] = xn;
        float4 w = ((const float4*)Wb)[c0 + r];
        p0 += xn * w.x; p1 += xn * w.y; p2 += xn * w.z; p3 += xn * w.w;
      }
    }
  // store LN'd row as bf16 (8B per (kc,pr) chunk, same rounding as before)
  #pragma unroll
  for (int kc = 0; kc < 4; kc++)
    #pragma unroll
    for (int pr = 0; pr < 2; pr++) {
      int o = kc * 8 + pr * 4;
      uint2 px;
      px.x = pack2(xv[o + 1], xv[o]);       // low ushort = lower dim
      px.x = (unsigned int)f2bf(xv[o]) | ((unsigned int)f2bf(xv[o + 1]) << 16);
      px.y = (unsigned int)f2bf(xv[o + 2]) | ((unsigned int)f2bf(xv[o + 3]) << 16);
      *(uint2*)(xln + (size_t)myrow * 128 + kc * 32 + g * 8 + pr * 4) = px;
    }
  p0 += __shfl_xor(p0, 16, 64); p0 += __shfl_xor(p0, 32, 64);
  p1 += __shfl_xor(p1, 16, 64); p1 += __shfl_xor(p1, 32, 64);
  p2 += __shfl_xor(p2, 16, 64); p2 += __shfl_xor(p2, 32, 64);
  p3 += __shfl_xor(p3, 16, 64); p3 += __shfl_xor(p3, 32, 64);
  if (g == 0) {
    const float l2e = 1.4426950408889634f;
    biasB[0 * NPOS + myrow] = f2bf(p0 * l2e);
    biasB[1 * NPOS + myrow] = f2bf(p1 * l2e);
    biasB[2 * NPOS + myrow] = f2bf(p2 * l2e);
    biasB[3 * NPOS + myrow] = f2bf(p3 * l2e);
  }
}

// ---------------- K2: head-slice proj + attention + gate ----------------
// grid 1024 remapped: i = bid&255, h = bid>>8 -> all 4 h-blocks of a
// row-block share an XCD (L2-hit on xln re-reads). Wave wv owns rows
// wv*32..+32: loads bf16 x_ln a-frags directly (no LN), projects head h's
// 32-dim Q/K/V/gate slices (K->LDS, V^T->LDS, Q->wave LDS, gate in regs),
// one barrier, then attention with hoisted biasB loads.
#define KS 40    // Klds row stride (ushorts; 80B: b128-aligned, 2-way banks)
#define VS 264   // VTlds row stride (ushorts; keys 256 + 8 pad)
#define QS 40    // qstg row stride
#define PST 40   // P-stage row stride
__global__ __launch_bounds__(512, 2) void k_attn2(
    const ushort* __restrict__ xln, const ushort* __restrict__ WT,
    const float* __restrict__ bg, const ushort* __restrict__ biasB,
    ushort* __restrict__ gctx) {
  __shared__ __align__(16) ushort Klds[256 * KS];    // 20480 B
  __shared__ __align__(16) ushort VTlds[32 * VS];    // 16896 B
  __shared__ __align__(16) ushort qstg[8][32 * QS];  // 20480 B
  __shared__ __align__(16) ushort pstg[8][16 * PST]; // 10240 B
  int i = blockIdx.x & 255, h = blockIdx.x >> 8;     // XCD-friendly remap
  int t = threadIdx.x, wv = t >> 6, lane = t & 63;
  int n = lane & 15, g = lane >> 4;
  int r0 = wv * 32;

  // ---- phase A: load LN'd rows as MFMA a-frags (bf16, direct) ----
  bf16x8 a[2][4];
  const ushort* xb = xln + ((size_t)i * 256 + r0) * 128;
  #pragma unroll
  for (int c = 0; c < 2; c++)
    #pragma unroll
    for (int kc = 0; kc < 4; kc++)
      a[c][kc] = *(const bf16x8*)(xb + (size_t)(c * 16 + n) * 128 + kc * 32 + g * 8);

  // ---- phase A2: 4 head-slice projections (32 cols each) ----
  f32x4 gs[2][2];   // gate (sigmoid applied), lane-mapped same as PV output
  #pragma unroll
  for (int sect = 0; sect < 4; sect++) {
    bf16x8 b[2][4];
    #pragma unroll
    for (int ntl = 0; ntl < 2; ntl++)
      #pragma unroll
      for (int kc = 0; kc < 4; kc++)
        b[ntl][kc] = *(const bf16x8*)(WT + (size_t)(sect * 128 + h * 32 + ntl * 16 + n) * 128 + kc * 32 + g * 8);
    #pragma unroll
    for (int c = 0; c < 2; c++) {
      f32x4 acc[2];
      #pragma unroll
      for (int ntl = 0; ntl < 2; ntl++) {
        f32x4 cc = {0.f, 0.f, 0.f, 0.f};
        #pragma unroll
        for (int kc = 0; kc < 4; kc++)
          cc = __builtin_amdgcn_mfma_f32_16x16x32_bf16(a[c][kc], b[ntl][kc], cc, 0, 0, 0);
        acc[ntl] = cc;
      }
      // acc[ntl][r] = proj[row r0+c*16+g*4+r][dim ntl*16+n] (head-local dim)
      if (sect == 0) {          // Q -> wave-private LDS [query][dim]
        #pragma unroll
        for (int ntl = 0; ntl < 2; ntl++)
          #pragma unroll
          for (int r = 0; r < 4; r++)
            qstg[wv][(c * 16 + g * 4 + r) * QS + ntl * 16 + n] = f2bf(acc[ntl][r]);
      } else if (sect == 1) {   // K -> shared LDS [key][dim]
        #pragma unroll
        for (int ntl = 0; ntl < 2; ntl++)
          #pragma unroll
          for (int r = 0; r < 4; r++)
            Klds[(r0 + c * 16 + g * 4 + r) * KS + ntl * 16 + n] = f2bf(acc[ntl][r]);
      } else if (sect == 2) {   // V -> shared LDS transposed [dim][key]
        #pragma unroll
        for (int ntl = 0; ntl < 2; ntl++) {
          uint2 vp;
          vp.x = (unsigned int)f2bf(acc[ntl][0]) | ((unsigned int)f2bf(acc[ntl][1]) << 16);
          vp.y = (unsigned int)f2bf(acc[ntl][2]) | ((unsigned int)f2bf(acc[ntl][3]) << 16);
          *(uint2*)(&VTlds[(ntl * 16 + n) * VS + r0 + c * 16 + g * 4]) = vp;
        }
      } else {                  // gate: keep in registers
        #pragma unroll
        for (int ntl = 0; ntl < 2; ntl++)
          #pragma unroll
          for (int r = 0; r < 4; r++)
            gs[c][ntl][r] = 1.0f / (1.0f + __expf(-(acc[ntl][r] + bg[h * 32 + ntl * 16 + n])));
      }
    }
  }
  __syncthreads();

  // ---- phase B: attention for the wave's 32 queries (2 tiles of 16) ----
  const ushort* bb = biasB + (size_t)h * NPOS;
  ushort* Pw = pstg[wv];
  #pragma unroll
  for (int tt = 0; tt < 2; tt++) {
    int j0 = r0 + tt * 16;
    bf16x8 bq = *(const bf16x8*)(&qstg[wv][(tt * 16 + n) * QS + g * 8]);
    // hoist all 16 bias loads (independent, one vmcnt train)
    uint2 bv[16];
    #pragma unroll
    for (int kt = 0; kt < 16; kt++)
      bv[kt] = *(const uint2*)(bb + (size_t)(j0 + n) * 256 + kt * 16 + g * 4);
    f32x4 s[16];
    #pragma unroll
    for (int kt = 0; kt < 16; kt++) {
      bf16x8 ak = *(const bf16x8*)(&Klds[(kt * 16 + n) * KS + g * 8]);
      f32x4 cc;
      cc[0] = lo_bf(bv[kt].x); cc[1] = hi_bf(bv[kt].x);
      cc[2] = lo_bf(bv[kt].y); cc[3] = hi_bf(bv[kt].y);
      s[kt] = __builtin_amdgcn_mfma_f32_16x16x32_bf16(ak, bq, cc, 0, 0, 0);
    }
    // softmax: exp2 (log2e pre-folded), no max-sub (scores bounded ~|2|)
    f32x4 a4 = {0.f, 0.f, 0.f, 0.f};
    #pragma unroll
    for (int kt = 0; kt < 16; kt++) {
      #pragma unroll
      for (int r = 0; r < 4; r++) s[kt][r] = EXP2F(s[kt][r]);
      a4 += s[kt];
    }
    float smm = (a4[0] + a4[1]) + (a4[2] + a4[3]);
    smm += __shfl_xor(smm, 16, 64);
    smm += __shfl_xor(smm, 32, 64);
    float inv = RCPF(smm);
    f32x4 ctx0 = {0.f, 0.f, 0.f, 0.f}, ctx1 = {0.f, 0.f, 0.f, 0.f};
    #pragma unroll
    for (int c8 = 0; c8 < 8; c8++) {
      #pragma unroll
      for (int t2 = 0; t2 < 2; t2++) {
        int kt = c8 * 2 + t2;
        uint2 pp;
        pp.x = permpack(s[kt][1] * inv, s[kt][0] * inv);
        pp.y = permpack(s[kt][3] * inv, s[kt][2] * inv);
        *(uint2*)(&Pw[n * PST + t2 * 16 + g * 4]) = pp;
      }
      bf16x8 ap = *(const bf16x8*)(&Pw[n * PST + g * 8]);
      bf16x8 v0 = *(const bf16x8*)(&VTlds[(size_t)n * VS + c8 * 32 + g * 8]);
      bf16x8 v1 = *(const bf16x8*)(&VTlds[(size_t)(16 + n) * VS + c8 * 32 + g * 8]);
      ctx0 = __builtin_amdgcn_mfma_f32_16x16x32_bf16(ap, v0, ctx0, 0, 0, 0);
      ctx1 = __builtin_amdgcn_mfma_f32_16x16x32_bf16(ap, v1, ctx1, 0, 0, 0);
    }
    // gate in registers (identical lane mapping), direct global store
    #pragma unroll
    for (int r = 0; r < 4; r++) {
      size_t pos = (size_t)i * 256 + j0 + g * 4 + r;
      gctx[pos * 128 + h * 32 + n]      = f2bf(ctx0[r] * gs[tt][0][r]);
      gctx[pos * 128 + h * 32 + 16 + n] = f2bf(ctx1[r] * gs[tt][1][r]);
    }
  }
}

// ---------------- K3: out-proj + bias + residual ----------------
__global__ __launch_bounds__(128, 4) void k_out(
    const ushort* __restrict__ gctx, const ushort* __restrict__ WoT,
    const float* __restrict__ bo, const float* __restrict__ in0,
    float* __restrict__ out) {
  __shared__ __align__(16) float CT[16 * 132];   // 8448B
  int t = threadIdx.x, wv = t >> 6, lane = t & 63;
  int n = lane & 15, g = lane >> 4;
  int row0 = blockIdx.x * 16;
  bf16x8 a[4];
  #pragma unroll
  for (int kc = 0; kc < 4; kc++)
    a[kc] = *(const bf16x8*)(gctx + (size_t)(row0 + n) * 128 + kc * 32 + g * 8);
  #pragma unroll
  for (int ntl2 = 0; ntl2 < 4; ntl2++) {
    int ntl = wv * 4 + ntl2;
    f32x4 acc = {0.f, 0.f, 0.f, 0.f};
    #pragma unroll
    for (int kc = 0; kc < 4; kc++) {
      bf16x8 b = *(const bf16x8*)(WoT + (size_t)(ntl * 16 + n) * 128 + kc * 32 + g * 8);
      acc = __builtin_amdgcn_mfma_f32_16x16x32_bf16(a[kc], b, acc, 0, 0, 0);
    }
    float bov = bo[ntl * 16 + n];
    #pragma unroll
    for (int r = 0; r < 4; r++)
      CT[(g * 4 + r) * 132 + ntl * 16 + n] = acc[r] + bov;
  }
  __syncthreads();
  #pragma unroll
  for (int it = 0; it < 4; it++) {
    int c = it * 128 + t;
    int row = c >> 5, off = (c & 31) * 4;
    f32x4 v = *(const f32x4*)(&CT[row * 132 + off]);
    size_t o = (size_t)(row0 + row) * 128 + off;
    f32x4 r4 = *(const f32x4*)(in0 + o);
    v[0] += r4[0]; v[1] += r4[1]; v[2] += r4[2]; v[3] += r4[3];
    *(f32x4*)(out + o) = v;
  }
}

extern "C" void kernel_launch(void* const* d_in, const int* in_sizes, int n_in,
                              void* d_out, int out_size, void* d_ws, size_t ws_size,
                              hipStream_t stream) {
  const float* in0   = (const float*)d_in[0];
  const float* gamma = (const float*)d_in[1];
  const float* beta  = (const float*)d_in[2];
  const float* Wq    = (const float*)d_in[3];
  const float* Wk    = (const float*)d_in[4];
  const float* Wv    = (const float*)d_in[5];
  const float* Wb    = (const float*)d_in[6];
  const float* Wg    = (const float*)d_in[7];
  const float* bg    = (const float*)d_in[8];
  const float* Wo    = (const float*)d_in[9];
  const float* bo    = (const float*)d_in[10];
  float* out = (float*)d_out;
  char* ws = (char*)d_ws;

  const size_t MB = 1024 * 1024;
  ushort* gctx  = (ushort*)(ws);              // 16 MB: [pos][128]
  ushort* xln   = (ushort*)(ws + 16 * MB);    // 16 MB: LN'd x, bf16 [pos][128]
  ushort* biasB = (ushort*)(ws + 32 * MB);    // 512 KB: [h][j*256+k] * log2e
  ushort* WT    = (ushort*)(ws + 33 * MB);    // 128 KB
  ushort* WoT   = (ushort*)(ws + 33 * MB + 128 * 1024);  // 32 KB

  k_pack <<<320, 256, 0, stream>>>(Wq, Wk, Wv, Wg, Wo, WT, WoT);
  k_ln   <<<2048, 128, 0, stream>>>(in0, gamma, beta, Wb, xln, biasB);
  k_attn2<<<1024, 512, 0, stream>>>(xln, WT, bg, biasB, gctx);
  k_out  <<<4096, 128, 0, stream>>>(gctx, WoT, bo, in0, out);
}